// Round 7
// baseline (3808.348 us; speedup 1.0000x reference)
//
#include <hip/hip_runtime.h>
#include <math.h>

#define NB 8
#define NV 64
#define NM 1024
#define NR 3
#define NT 16
#define KR 8
#define RTOT 48                 // NR*NT
#define RADIUSF 40.0f
#define TWO_PIF 6.283185307179586f

// ---------------------------------------------------------------------------
// Pair geometry: replicates the reference bilinear polar binning exactly.
// ---------------------------------------------------------------------------
__device__ __forceinline__ void pair_geom(float relx, float rely, float mask,
                                          float& valid, float& win,
                                          int bin[4], float cw[4]) {
    float d = sqrtf(relx * relx + rely * rely + 1e-12f);
    valid = (d < RADIUSF) ? mask : 0.0f;
    float q = d * (1.0f / RADIUSF);
    float w1 = fmaxf(1.0f - q * q, 0.0f);
    win = w1 * w1 * w1;
    float u = fminf(fmaxf(q, 0.0f), 1.0f) * (float)(NR - 1);
    float r0f = floorf(u);
    float wr = u - r0f;
    int r0 = (int)r0f;
    int r1 = min(r0 + 1, NR - 1);
    float a = atan2f(rely, relx) * (1.0f / TWO_PIF);
    a = a - floorf(a);                  // mod 1 -> [0,1)
    float t = a * (float)NT;
    float t0f = floorf(t);
    float wt = t - t0f;
    int t0 = ((int)t0f) & (NT - 1);
    int t1 = (t0 + 1) & (NT - 1);
    bin[0] = r0 * NT + t0; cw[0] = (1.0f - wr) * (1.0f - wt);
    bin[1] = r0 * NT + t1; cw[1] = (1.0f - wr) * wt;
    bin[2] = r1 * NT + t0; cw[2] = wr * (1.0f - wt);
    bin[3] = r1 * NT + t1; cw[3] = wr * wt;
}

// ---------------------------------------------------------------------------
// Step-0 pair weights. One wave per (b,n).  [R3 verbatim]
// ---------------------------------------------------------------------------
__global__ __launch_bounds__(64) void k_pairs0(const float* __restrict__ p,
                                               const float* __restrict__ car_mask,
                                               float* __restrict__ w4,
                                               int* __restrict__ bin4) {
    int b = blockIdx.x >> 6, n = blockIdx.x & 63;
    int s = threadIdx.x;
    float dx = p[(b * NV + n) * 2 + 0], dy = p[(b * NV + n) * 2 + 1];
    float relx = p[(b * NV + s) * 2 + 0] - dx;
    float rely = p[(b * NV + s) * 2 + 1] - dy;
    float valid, win; int bin[4]; float cw[4];
    pair_geom(relx, rely, car_mask[b * NV + s], valid, win, bin, cw);
    float c = valid;
#pragma unroll
    for (int off = 32; off > 0; off >>= 1) c += __shfl_xor(c, off);
    float bw = valid * win / fmaxf(c, 1.0f);
    int base = (blockIdx.x * NV + s) * 4;
#pragma unroll
    for (int q = 0; q < 4; ++q) { w4[base + q] = bw * cw[q]; bin4[base + q] = bin[q]; }
}

// ---------------------------------------------------------------------------
// advance: outputs[t-1], position update, pair weights, SINGLE-PASS map
// encoder (unnormalized G + count, scale at contraction), back gate.
// ---------------------------------------------------------------------------
__global__ __launch_bounds__(256) void k_advance(int t,
        const float* __restrict__ pprev, float* __restrict__ pcur,
        const float* __restrict__ outD, float* __restrict__ feat,
        const float* __restrict__ w_rho1, const float* __restrict__ WdBack,
        const float* __restrict__ Kmap, const float* __restrict__ map_p,
        const float* __restrict__ map_feat, const float* __restrict__ map_mask,
        const float* __restrict__ car_mask,
        float* __restrict__ w4, int* __restrict__ bin4,
        float* __restrict__ out) {
    __shared__ float s_out0[NV * KR];     // outputD[b,s,0,:]
    __shared__ float s_own[3 * KR];       // outputD[b,n,:,:]
    __shared__ float s_psrc[NV * 2];      // updated source positions
    __shared__ float s_G4[4 * 96];        // per-wave map accumulators
    __shared__ float s_G[96];
    __shared__ float s_wred[4];
    __shared__ float s_K[RTOT * KR * KR * 2];   // 24KB K_map
    __shared__ float s_w2[KR * 2];

    int tid = threadIdx.x;
    int b = blockIdx.x >> 6, n = blockIdx.x & 63;

    for (int i = tid; i < NV * KR; i += 256)
        s_out0[i] = outD[(b * NV + (i >> 3)) * 24 + (i & 7)];
    if (tid < 24) s_own[tid] = outD[(b * NV + n) * 24 + tid];
    if (tid < 16) {
        int m = tid >> 1, dd = tid & 1;
        float ang = TWO_PIF * (float)m / (float)KR;
        float sn, cs;
        sincosf(ang, &sn, &cs);
        float w0 = w_rho1[0], wq = w_rho1[1];
        s_w2[tid] = (dd == 0) ? (w0 * cs - wq * sn) : (w0 * sn + wq * cs);
    }
    for (int i = tid; i < RTOT * KR * KR * 2; i += 256) s_K[i] = Kmap[i];
    if (tid < 96) { s_G4[tid] = 0.f; s_G4[96 + tid] = 0.f; s_G4[192 + tid] = 0.f; s_G4[288 + tid] = 0.f; }
    __syncthreads();

    // ---- per-source position update
    if (tid < NV) {
        int s = tid;
        float dx0 = 0.0f, dy0 = 0.0f;
#pragma unroll
        for (int m = 0; m < KR; ++m) {
            float v = s_out0[s * KR + m];
            dx0 = fmaf(v, s_w2[m * 2 + 0], dx0);
            dy0 = fmaf(v, s_w2[m * 2 + 1], dy0);
        }
        s_psrc[s * 2 + 0] = pprev[(b * NV + s) * 2 + 0] + dx0;
        s_psrc[s * 2 + 1] = pprev[(b * NV + s) * 2 + 1] + dy0;
    }
    // ---- outputs[t-1] = reg2rho1(output_{t-1}) (+ p_{t-1} on channel 0)
    if (tid >= 64 && tid < 70) {
        int r = tid - 64, c = r >> 1, dd = r & 1;
        float acc = 0.0f;
#pragma unroll
        for (int m = 0; m < KR; ++m)
            acc = fmaf(s_own[c * KR + m], s_w2[m * 2 + dd], acc);
        if (c == 0) acc += pprev[(b * NV + n) * 2 + dd];
        out[(((t - 1) * NB + b) * NV + n) * 6 + c * 2 + dd] = acc;
    }
    __syncthreads();
    if (tid < 2) pcur[(b * NV + n) * 2 + tid] = s_psrc[n * 2 + tid];

    float pdx = s_psrc[n * 2 + 0], pdy = s_psrc[n * 2 + 1];

    // ---- vehicle pair weights (wave 0)
    if (tid < NV) {
        int s = tid;
        float relx = s_psrc[s * 2 + 0] - pdx, rely = s_psrc[s * 2 + 1] - pdy;
        float valid, win; int bin[4]; float cw[4];
        pair_geom(relx, rely, car_mask[b * NV + s], valid, win, bin, cw);
        float c = valid;
#pragma unroll
        for (int off = 32; off > 0; off >>= 1) c += __shfl_xor(c, off);
        float bw = valid * win / fmaxf(c, 1.0f);
        int base = (blockIdx.x * NV + s) * 4;
#pragma unroll
        for (int q = 0; q < 4; ++q) { w4[base + q] = bw * cw[q]; bin4[base + q] = bin[q]; }
    }

    // ---- map: single pass (unnormalized accumulate + count)
    float lc = 0.0f;
    float* myG = &s_G4[(tid >> 6) * 96];
#pragma unroll
    for (int j = 0; j < NM / 256; ++j) {
        int s = tid + j * 256;
        float2 mp = *(const float2*)&map_p[(b * NM + s) * 2];
        float relx = mp.x - pdx, rely = mp.y - pdy;
        float valid, win; int bin[4]; float cw[4];
        pair_geom(relx, rely, map_mask[b * NM + s], valid, win, bin, cw);
        lc += valid;
        float ww = valid * win;
        if (ww > 0.0f) {
            float2 f2 = *(const float2*)&map_feat[(b * NM + s) * 2];
#pragma unroll
            for (int q = 0; q < 4; ++q) {
                float w = ww * cw[q];
                atomicAdd(&myG[bin[q] * 2 + 0], w * f2.x);
                atomicAdd(&myG[bin[q] * 2 + 1], w * f2.y);
            }
        }
    }
#pragma unroll
    for (int off = 32; off > 0; off >>= 1) lc += __shfl_xor(lc, off);
    if ((tid & 63) == 0) s_wred[tid >> 6] = lc;
    __syncthreads();
    if (tid < 96) s_G[tid] = s_G4[tid] + s_G4[96 + tid] + s_G4[192 + tid] + s_G4[288 + tid];
    __syncthreads();
    float invc = 1.0f / fmaxf(s_wred[0] + s_wred[1] + s_wred[2] + s_wred[3], 1.0f);

    // ---- map encoder contraction (scale by invc at the end)
    if (tid < 64) {
        int o = tid >> 3, m = tid & 7;
        float acc = 0.0f;
        for (int rt = 0; rt < RTOT; ++rt) {
            acc = fmaf(s_K[rt * 128 + o * 16 + m * 2 + 0], s_G[rt * 2 + 0], acc);
            acc = fmaf(s_K[rt * 128 + o * 16 + m * 2 + 1], s_G[rt * 2 + 1], acc);
        }
        feat[(b * NV + n) * 192 + (16 + o) * 8 + m] = fmaxf(acc * invc, 0.0f);
    }
    // ---- back gate
    if (tid < 128) {
        int i = tid >> 3, m = tid & 7;
        float acc = 0.0f;
#pragma unroll
        for (int c = 0; c < 3; ++c)
#pragma unroll
            for (int l = 0; l < KR; ++l)
                acc = fmaf(WdBack[(i * 3 + c) * 8 + l], s_own[c * 8 + ((m - l) & 7)], acc);
        float bk = tanhf(acc);
        int idx = (b * NV + n) * 192 + i * 8 + m;
        feat[idx] = feat[idx] * bk;
    }
}

// ---------------------------------------------------------------------------
// One-time K transpose: KT[chunk j][pair p].  [R6 verbatim]
// ---------------------------------------------------------------------------
__global__ __launch_bounds__(256) void k_trans(
        const float* __restrict__ Kv, const float* __restrict__ K1g,
        const float* __restrict__ K2g, float4* __restrict__ KTv,
        float4* __restrict__ KT1, float4* __restrict__ KT2) {
    int idx = blockIdx.x * 256 + threadIdx.x;
    if (idx < 48 * 384) {
        int j = idx / 384, p = idx % 384;
        KTv[idx] = *(const float4*)(Kv + p * 192 + j * 4);
    } else if (idx < 48 * 384 + 16 * 384) {
        int r = idx - 48 * 384;
        int j = r / 384, p = r % 384;
        KT1[r] = *(const float4*)(K1g + p * 64 + j * 4);
    } else if (idx < 48 * 384 + 16 * 384 + 16 * 144) {
        int r = idx - (48 * 384 + 16 * 384);
        int j = r / 144, p = r % 144;
        KT2[r] = *(const float4*)(K2g + p * 64 + j * 4);
    }
}

// ---------------------------------------------------------------------------
// k_Hv: vehicle-layer H, 4 sources per block (amortize the 294KB KT reads).
// Hv[bs, rt, o, m] = sum_{i,l} Kv[rt,o,i,l] * feat[bs, i, (m-l)&7]
// ---------------------------------------------------------------------------
__global__ __launch_bounds__(256) void k_Hv(const float* __restrict__ feat,
        const float4* __restrict__ KT, float* __restrict__ H) {
    __shared__ __align__(16) float s_f[4 * 192];
    int tid = threadIdx.x;
    int bs0 = blockIdx.x * 4;
    for (int i = tid; i < 4 * 192; i += 256)
        s_f[i] = feat[bs0 * 192 + i];
    __syncthreads();
    for (int p = tid; p < 384; p += 256) {
        float acc[4][KR];
#pragma unroll
        for (int src = 0; src < 4; ++src)
#pragma unroll
            for (int m = 0; m < KR; ++m) acc[src][m] = 0.f;
        for (int i = 0; i < 24; ++i) {
            float4 k0 = KT[(2 * i) * 384 + p];
            float4 k1 = KT[(2 * i + 1) * 384 + p];
            float kk[8] = {k0.x, k0.y, k0.z, k0.w, k1.x, k1.y, k1.z, k1.w};
#pragma unroll
            for (int src = 0; src < 4; ++src) {
                float ff[8];
                *(float4*)&ff[0] = *(const float4*)&s_f[src * 192 + i * 8];
                *(float4*)&ff[4] = *(const float4*)&s_f[src * 192 + i * 8 + 4];
#pragma unroll
                for (int l = 0; l < KR; ++l) {
                    float kl = kk[l];
#pragma unroll
                    for (int m = 0; m < KR; ++m)
                        acc[src][m] = fmaf(kl, ff[(m - l) & 7], acc[src][m]);
                }
            }
        }
        int rt = p >> 3, o = p & 7;
#pragma unroll
        for (int src = 0; src < 4; ++src) {
            float* hr = H + (size_t)((bs0 + src) * RTOT + rt) * 64 + o * KR;
#pragma unroll
            for (int m = 0; m < KR; ++m) hr[m] = acc[src][m];
        }
    }
}

// ---------------------------------------------------------------------------
// k_aggH: fused [aggregate layer L -> out] + [H for layer L+1 from relu(out)].
// Phase 1 == proven k_agg (OCH=8 -> HS=64); phase 2 == h_pair on own block.
// Separate H buffers per layer: no cross-block race.
// ---------------------------------------------------------------------------
template<int ICH, bool RELU_IN, bool RESID, int OCH2>
__global__ __launch_bounds__(256) void k_aggH(const float* __restrict__ inb,
        const float* __restrict__ H, const float* __restrict__ Wd,
        const float* __restrict__ w4, const int* __restrict__ bin4,
        const float4* __restrict__ KT2, float* __restrict__ outb,
        float* __restrict__ Hout) {
    constexpr int NC = ICH * KR;
    constexpr int HS = 64;                 // OCH = 8
    constexpr int NPAIR2 = RTOT * OCH2;    // 384 or 144
    constexpr int HS2 = OCH2 * KR;
    __shared__ float s_w[256];
    __shared__ int   s_b[256];
    __shared__ float s_in[NC];
    __shared__ float s_part[4 * HS];
    __shared__ __align__(16) float s_f2[HS];
    int tid = threadIdx.x, bn = blockIdx.x, b = bn >> 6;
    s_w[tid] = w4[bn * 256 + tid];
    s_b[tid] = bin4[bn * 256 + tid];
    if (tid < NC) s_in[tid] = inb[bn * NC + tid];
    __syncthreads();
    // ---- phase 1: aggregation
    {
        int w = tid >> 6, c = tid & 63;
        float acc = 0.f;
        for (int j = 0; j < 64; ++j) {
            int idx = w * 64 + j;
            float we = s_w[idx];
            if (we != 0.f) {
                int s = idx >> 2;
                acc = fmaf(we, H[(size_t)((b * NV + s) * RTOT + s_b[idx]) * HS + c], acc);
            }
        }
        s_part[w * HS + c] = acc;
    }
    __syncthreads();
    if (tid < HS) {
        float tot = s_part[tid] + s_part[HS + tid] + s_part[2 * HS + tid] + s_part[3 * HS + tid];
        int o = tid / KR, m = tid & 7;
#pragma unroll
        for (int i = 0; i < ICH; ++i) {
            const float* Wr = Wd + (o * ICH + i) * KR;
#pragma unroll
            for (int l = 0; l < KR; ++l) {
                float v = s_in[i * KR + ((m - l) & 7)];
                if (RELU_IN) v = fmaxf(v, 0.f);
                tot = fmaf(Wr[l], v, tot);
            }
        }
        if (RESID) tot += s_in[tid];
        outb[bn * HS + tid] = tot;
        s_f2[tid] = fmaxf(tot, 0.f);       // next layer consumes relu(out)
    }
    __syncthreads();
    // ---- phase 2: H for next layer (ICH2 = 8)
    for (int p = tid; p < NPAIR2; p += 256) {
        float acc2[KR];
#pragma unroll
        for (int m = 0; m < KR; ++m) acc2[m] = 0.f;
#pragma unroll
        for (int i = 0; i < 8; ++i) {
            float4 k0 = KT2[(2 * i) * NPAIR2 + p];
            float4 k1 = KT2[(2 * i + 1) * NPAIR2 + p];
            float kk[8] = {k0.x, k0.y, k0.z, k0.w, k1.x, k1.y, k1.z, k1.w};
            float ff[8];
            *(float4*)&ff[0] = *(const float4*)&s_f2[i * 8];
            *(float4*)&ff[4] = *(const float4*)&s_f2[i * 8 + 4];
#pragma unroll
            for (int l = 0; l < KR; ++l) {
                float kl = kk[l];
#pragma unroll
                for (int m = 0; m < KR; ++m)
                    acc2[m] = fmaf(kl, ff[(m - l) & 7], acc2[m]);
            }
        }
        int rt = p / OCH2, o = p - rt * OCH2;
        float* hr = Hout + (size_t)(bn * RTOT + rt) * HS2 + o * KR;
#pragma unroll
        for (int m = 0; m < KR; ++m) hr[m] = acc2[m];
    }
}

// ---------------------------------------------------------------------------
// k_agg: standalone aggregation (last layer).  [R6 verbatim]
// ---------------------------------------------------------------------------
template<int ICH, int OCH, bool RELU_IN, bool RESID, bool RELU_OUT>
__global__ __launch_bounds__(256) void k_agg(const float* __restrict__ inb,
        const float* __restrict__ H, const float* __restrict__ Wd,
        const float* __restrict__ w4, const int* __restrict__ bin4,
        float* __restrict__ outb) {
    constexpr int NC = ICH * KR;
    constexpr int HS = OCH * KR;
    __shared__ float s_w[256];
    __shared__ int   s_b[256];
    __shared__ float s_in[NC];
    __shared__ float s_part[4 * HS];
    int tid = threadIdx.x, bn = blockIdx.x, b = bn >> 6;
    s_w[tid] = w4[bn * 256 + tid];
    s_b[tid] = bin4[bn * 256 + tid];
    if (tid < NC) s_in[tid] = inb[bn * NC + tid];
    __syncthreads();
    int w = tid >> 6, c = tid & 63;
    if (c < HS) {
        float acc = 0.f;
        for (int j = 0; j < 64; ++j) {
            int idx = w * 64 + j;
            float we = s_w[idx];
            if (we != 0.f) {
                int s = idx >> 2;
                int bin = s_b[idx];
                acc = fmaf(we, H[(size_t)((b * NV + s) * RTOT + bin) * HS + c], acc);
            }
        }
        s_part[w * HS + c] = acc;
    }
    __syncthreads();
    if (tid < HS) {
        float tot = s_part[tid] + s_part[HS + tid] + s_part[2 * HS + tid] + s_part[3 * HS + tid];
        int o = tid / KR, m = tid & 7;
#pragma unroll
        for (int i = 0; i < ICH; ++i) {
            const float* Wr = Wd + (o * ICH + i) * KR;
#pragma unroll
            for (int l = 0; l < KR; ++l) {
                float v = s_in[i * KR + ((m - l) & 7)];
                if (RELU_IN) v = fmaxf(v, 0.f);
                tot = fmaf(Wr[l], v, tot);
            }
        }
        if (RESID) tot += s_in[tid];
        if (RELU_OUT) tot = fmaxf(tot, 0.f);
        outb[bn * HS + tid] = tot;
    }
}

// ---------------------------------------------------------------------------
// FALLBACK PATH: fused conv (gather-then-contract).  [R3 verbatim]
// ---------------------------------------------------------------------------
template<int ICH, int OCH, bool RELU_IN, bool RESID, bool RELU_OUT>
__global__ __launch_bounds__(256) void k_conv(
        const float* __restrict__ inb, const float* __restrict__ Kg,
        const float* __restrict__ Wd, const float* __restrict__ w4,
        const int* __restrict__ bin4, float* __restrict__ outb) {
    constexpr int NC = ICH * KR;
    constexpr int NOUT = OCH * KR;
    constexpr int NQ = (OCH == 8) ? 32 : 64;
    constexpr int NG = 256 / NC;
    constexpr int GP = 12;

    __shared__ __align__(16) float G[RTOT * ICH * GP];
    __shared__ float s_w4[NV * 4];
    __shared__ int   s_b4[NV * 4];
    __shared__ __align__(16) float s_in[NC];

    int tid = threadIdx.x;
    int bn = blockIdx.x;
    int b = bn >> 6;

    for (int i = tid; i < RTOT * ICH * GP; i += 256) G[i] = 0.0f;
    s_w4[tid] = w4[bn * 256 + tid];
    s_b4[tid] = bin4[bn * 256 + tid];
    if (tid < NC) s_in[tid] = inb[bn * NC + tid];
    __syncthreads();

    if (tid < NC * NG) {
        int col = tid % NC, grp = tid / NC;
        int ci = col >> 3, cm = col & 7;
        for (int s = grp; s < NV; s += NG) {
            float v = inb[(b * NV + s) * NC + col];
            if (RELU_IN) v = fmaxf(v, 0.0f);
#pragma unroll
            for (int q = 0; q < 4; ++q) {
                float w = s_w4[s * 4 + q];
                if (w != 0.0f)
                    atomicAdd(&G[(s_b4[s * 4 + q] * ICH + ci) * GP + cm], w * v);
            }
        }
    }
    __syncthreads();

    const int q = tid & (NQ - 1);
    const int o = tid / NQ;
    if (o < OCH) {
        constexpr int ITERS = (RTOT * ICH) / NQ;
        float acc[KR];
#pragma unroll
        for (int m = 0; m < KR; ++m) acc[m] = 0.f;
#pragma unroll 2
        for (int j = 0; j < ITERS; ++j) {
            int f = j * NQ + q;
            int rt = f / ICH, i = f - rt * ICH;
            const float* Kr = Kg + ((rt * OCH + o) * ICH + i) * KR;
            const float* gr = &G[f * GP];
            float kk[8], gg[8];
            *(float4*)&kk[0] = *(const float4*)(Kr);
            *(float4*)&kk[4] = *(const float4*)(Kr + 4);
            *(float4*)&gg[0] = *(const float4*)(gr);
            *(float4*)&gg[4] = *(const float4*)(gr + 4);
#pragma unroll
            for (int l = 0; l < KR; ++l) {
                float kl = kk[l];
#pragma unroll
                for (int m = 0; m < KR; ++m)
                    acc[m] = fmaf(kl, gg[(m - l) & 7], acc[m]);
            }
        }
#pragma unroll
        for (int m = 0; m < KR; ++m) {
            acc[m] += __shfl_xor(acc[m], 1);
            acc[m] += __shfl_xor(acc[m], 2);
            acc[m] += __shfl_xor(acc[m], 4);
            acc[m] += __shfl_xor(acc[m], 8);
            acc[m] += __shfl_xor(acc[m], 16);
            if (NQ == 64) acc[m] += __shfl_xor(acc[m], 32);
        }
        if (q < KR) {
            float tot = acc[0];
#pragma unroll
            for (int m = 1; m < KR; ++m) if (q == m) tot = acc[m];
#pragma unroll
            for (int i = 0; i < ICH; ++i) {
                const float* Wr = Wd + (o * ICH + i) * KR;
#pragma unroll
                for (int l = 0; l < KR; ++l) {
                    float v = s_in[i * KR + ((q - l) & 7)];
                    if (RELU_IN) v = fmaxf(v, 0.0f);
                    tot = fmaf(Wr[l], v, tot);
                }
            }
            if (RESID) tot += s_in[o * KR + q];
            if (RELU_OUT) tot = fmaxf(tot, 0.f);
            outb[bn * NOUT + o * KR + q] = tot;
        }
    }
}

// ---------------------------------------------------------------------------
// Final write: outputs[29]
// ---------------------------------------------------------------------------
__global__ void k_final(const float* __restrict__ outD, const float* __restrict__ pcur,
                        const float* __restrict__ w_rho1, float* __restrict__ out) {
    int idx = blockIdx.x * blockDim.x + threadIdx.x;
    if (idx >= NB * NV * 6) return;
    int bn = idx / 6, r = idx % 6, c = r >> 1, dd = r & 1;
    float w0 = w_rho1[0], wq = w_rho1[1];
    float acc = 0.0f;
#pragma unroll
    for (int m = 0; m < KR; ++m) {
        float ang = TWO_PIF * (float)m / (float)KR;
        float sn, cs;
        sincosf(ang, &sn, &cs);
        float w2 = (dd == 0) ? (w0 * cs - wq * sn) : (w0 * sn + wq * cs);
        acc = fmaf(outD[bn * 24 + c * 8 + m], w2, acc);
    }
    if (c == 0) acc += pcur[bn * 2 + dd];
    out[(29 * NB * NV + bn) * 6 + r] = acc;
}

// ---------------------------------------------------------------------------
extern "C" void kernel_launch(void* const* d_in, const int* in_sizes, int n_in,
                              void* d_out, int out_size, void* d_ws, size_t ws_size,
                              hipStream_t stream) {
    const float* in_p     = (const float*)d_in[0];
    const float* in_feat  = (const float*)d_in[1];
    const float* map_p    = (const float*)d_in[2];
    const float* map_feat = (const float*)d_in[3];
    const float* car_mask = (const float*)d_in[4];
    const float* map_mask = (const float*)d_in[5];
    const float* Kv       = (const float*)d_in[6];
    const float* WdV      = (const float*)d_in[7];
    const float* K1       = (const float*)d_in[8];
    const float* Wd1      = (const float*)d_in[9];
    const float* K2       = (const float*)d_in[10];
    const float* Wd2      = (const float*)d_in[11];
    const float* WdBack   = (const float*)d_in[12];
    const float* w_rho1   = (const float*)d_in[13];
    const float* Kmap     = (const float*)d_in[14];

    float* ws   = (float*)d_ws;
    float* pbuf0 = ws;                       // 1024
    float* pbuf1 = ws + 1024;                // 1024
    float* feat  = ws + 2048;                // 98304  [512][192]
    float* out1  = ws + 100352;              // 32768  [512][64]
    float* out2  = ws + 133120;              // 32768  [512][64]
    float* outD  = ws + 165888;              // 12288  [512][24]
    float* w4    = ws + 178176;              // 131072 [512][256]
    int*   bin4  = (int*)(ws + 309248);      // 131072 ints -> ends 440320 fl
    float4* KTv  = (float4*)(ws + 440320);   // 73728 floats  [48][384] f4
    float4* KT1  = (float4*)(ws + 514048);   // 24576 floats  [16][384] f4
    float4* KT2  = (float4*)(ws + 538624);   // 9216 floats   [16][144] f4
    float* Hv    = ws + 547840;              // 1572864 [512][48][64]
    float* H1    = ws + 2120704;             // 1572864 [512][48][64]
    float* H2    = ws + 3693568;             // 589824  [512][48][24]
    float* out   = (float*)d_out;

    const size_t need_fast = (size_t)(3693568 + 589824) * sizeof(float); // 17.1 MB
    const bool fast = ws_size >= need_fast;

    hipMemcpyAsync(pbuf0, in_p, NB * NV * 2 * sizeof(float),
                   hipMemcpyDeviceToDevice, stream);
    hipMemcpyAsync(feat, in_feat, NB * NV * 24 * KR * sizeof(float),
                   hipMemcpyDeviceToDevice, stream);

    if (fast)
        k_trans<<<105, 256, 0, stream>>>(Kv, K1, K2, KTv, KT1, KT2);
    k_pairs0<<<NB * NV, 64, 0, stream>>>(pbuf0, car_mask, w4, bin4);

    auto decode_fast = [&]() {
        k_Hv<<<NB * NV / 4, 256, 0, stream>>>(feat, KTv, Hv);
        k_aggH<24, false, false, 8><<<NB * NV, 256, 0, stream>>>(feat, Hv, WdV, w4, bin4, KT1, out1, H1);
        k_aggH<8, true, true, 3><<<NB * NV, 256, 0, stream>>>(out1, H1, Wd1, w4, bin4, KT2, out2, H2);
        k_agg<8, 3, true, false, true><<<NB * NV, 256, 0, stream>>>(out2, H2, Wd2, w4, bin4, outD);
    };
    auto decode_safe = [&]() {
        k_conv<24, 8, false, false, false><<<NB * NV, 256, 0, stream>>>(feat, Kv, WdV, w4, bin4, out1);
        k_conv<8, 8, true, true, false><<<NB * NV, 256, 0, stream>>>(out1, K1, Wd1, w4, bin4, out2);
        k_conv<8, 3, true, false, true><<<NB * NV, 256, 0, stream>>>(out2, K2, Wd2, w4, bin4, outD);
    };
    auto decode = [&]() { if (fast) decode_fast(); else decode_safe(); };

    decode();
    for (int t = 1; t < 30; ++t) {
        float* pprev = (t & 1) ? pbuf0 : pbuf1;
        float* pcur  = (t & 1) ? pbuf1 : pbuf0;
        k_advance<<<NB * NV, 256, 0, stream>>>(t, pprev, pcur, outD, feat,
                                               w_rho1, WdBack, Kmap, map_p, map_feat,
                                               map_mask, car_mask, w4, bin4, out);
        decode();
    }
    k_final<<<12, 256, 0, stream>>>(outD, pbuf1, w_rho1, out);
}

// Round 8
// 1863.741 us; speedup vs baseline: 2.0434x; 2.0434x over previous
//
#include <hip/hip_runtime.h>
#include <math.h>

#define NB 8
#define NV 64
#define NM 1024
#define NR 3
#define NT 16
#define KR 8
#define RTOT 48                 // NR*NT
#define RADIUSF 40.0f
#define TWO_PIF 6.283185307179586f

// ---------------------------------------------------------------------------
// Pair geometry: replicates the reference bilinear polar binning exactly.
// ---------------------------------------------------------------------------
__device__ __forceinline__ void pair_geom(float relx, float rely, float mask,
                                          float& valid, float& win,
                                          int bin[4], float cw[4]) {
    float d = sqrtf(relx * relx + rely * rely + 1e-12f);
    valid = (d < RADIUSF) ? mask : 0.0f;
    float q = d * (1.0f / RADIUSF);
    float w1 = fmaxf(1.0f - q * q, 0.0f);
    win = w1 * w1 * w1;
    float u = fminf(fmaxf(q, 0.0f), 1.0f) * (float)(NR - 1);
    float r0f = floorf(u);
    float wr = u - r0f;
    int r0 = (int)r0f;
    int r1 = min(r0 + 1, NR - 1);
    float a = atan2f(rely, relx) * (1.0f / TWO_PIF);
    a = a - floorf(a);                  // mod 1 -> [0,1)
    float t = a * (float)NT;
    float t0f = floorf(t);
    float wt = t - t0f;
    int t0 = ((int)t0f) & (NT - 1);
    int t1 = (t0 + 1) & (NT - 1);
    bin[0] = r0 * NT + t0; cw[0] = (1.0f - wr) * (1.0f - wt);
    bin[1] = r0 * NT + t1; cw[1] = (1.0f - wr) * wt;
    bin[2] = r1 * NT + t0; cw[2] = wr * (1.0f - wt);
    bin[3] = r1 * NT + t1; cw[3] = wr * wt;
}

// ---------------------------------------------------------------------------
// Step-0 pair weights. One wave per (b,n).  [R3 verbatim]
// ---------------------------------------------------------------------------
__global__ __launch_bounds__(64) void k_pairs0(const float* __restrict__ p,
                                               const float* __restrict__ car_mask,
                                               float* __restrict__ w4,
                                               int* __restrict__ bin4) {
    int b = blockIdx.x >> 6, n = blockIdx.x & 63;
    int s = threadIdx.x;
    float dx = p[(b * NV + n) * 2 + 0], dy = p[(b * NV + n) * 2 + 1];
    float relx = p[(b * NV + s) * 2 + 0] - dx;
    float rely = p[(b * NV + s) * 2 + 1] - dy;
    float valid, win; int bin[4]; float cw[4];
    pair_geom(relx, rely, car_mask[b * NV + s], valid, win, bin, cw);
    float c = valid;
#pragma unroll
    for (int off = 32; off > 0; off >>= 1) c += __shfl_xor(c, off);
    float bw = valid * win / fmaxf(c, 1.0f);
    int base = (blockIdx.x * NV + s) * 4;
#pragma unroll
    for (int q = 0; q < 4; ++q) { w4[base + q] = bw * cw[q]; bin4[base + q] = bin[q]; }
}

// ---------------------------------------------------------------------------
// k_advHv: outputs[t-1], position update, pair weights, single-pass map
// encoder (Kmap read L2-direct), back gate, feat write, AND the vehicle-layer
// H for the own source row (fused tail; feat row already in LDS).
// ---------------------------------------------------------------------------
__global__ __launch_bounds__(256) void k_advHv(int t,
        const float* __restrict__ pprev, float* __restrict__ pcur,
        const float* __restrict__ outD, float* __restrict__ feat,
        const float* __restrict__ w_rho1, const float* __restrict__ WdBack,
        const float* __restrict__ Kmap, const float* __restrict__ map_p,
        const float* __restrict__ map_feat, const float* __restrict__ map_mask,
        const float* __restrict__ car_mask,
        float* __restrict__ w4, int* __restrict__ bin4,
        float* __restrict__ out,
        const float4* __restrict__ KTv, float* __restrict__ Hv, int doHv) {
    __shared__ float s_out0[NV * KR];     // outputD[b,s,0,:]
    __shared__ float s_own[3 * KR];       // outputD[b,n,:,:]
    __shared__ float s_psrc[NV * 2];      // updated source positions
    __shared__ float s_G4[4 * 96];        // per-wave map accumulators
    __shared__ float s_G[96];
    __shared__ float s_wred[4];
    __shared__ float s_w2[KR * 2];
    __shared__ __align__(16) float s_f2[192];   // new feat row (own)

    int tid = threadIdx.x;
    int bn = blockIdx.x, b = bn >> 6, n = bn & 63;

    for (int i = tid; i < NV * KR; i += 256)
        s_out0[i] = outD[(b * NV + (i >> 3)) * 24 + (i & 7)];
    if (tid < 24) s_own[tid] = outD[(b * NV + n) * 24 + tid];
    if (tid >= 32 && tid < 48) {
        int r = tid - 32, m = r >> 1, dd = r & 1;
        float ang = TWO_PIF * (float)m / (float)KR;
        float sn, cs;
        sincosf(ang, &sn, &cs);
        float w0 = w_rho1[0], wq = w_rho1[1];
        s_w2[r] = (dd == 0) ? (w0 * cs - wq * sn) : (w0 * sn + wq * cs);
    }
    if (tid < 96) { s_G4[tid] = 0.f; s_G4[96 + tid] = 0.f; s_G4[192 + tid] = 0.f; s_G4[288 + tid] = 0.f; }
    __syncthreads();

    // ---- per-source position update
    if (tid < NV) {
        int s = tid;
        float dx0 = 0.0f, dy0 = 0.0f;
#pragma unroll
        for (int m = 0; m < KR; ++m) {
            float v = s_out0[s * KR + m];
            dx0 = fmaf(v, s_w2[m * 2 + 0], dx0);
            dy0 = fmaf(v, s_w2[m * 2 + 1], dy0);
        }
        s_psrc[s * 2 + 0] = pprev[(b * NV + s) * 2 + 0] + dx0;
        s_psrc[s * 2 + 1] = pprev[(b * NV + s) * 2 + 1] + dy0;
    }
    // ---- outputs[t-1] = reg2rho1(output_{t-1}) (+ p_{t-1} on channel 0)
    if (tid >= 64 && tid < 70) {
        int r = tid - 64, c = r >> 1, dd = r & 1;
        float acc = 0.0f;
#pragma unroll
        for (int m = 0; m < KR; ++m)
            acc = fmaf(s_own[c * KR + m], s_w2[m * 2 + dd], acc);
        if (c == 0) acc += pprev[(b * NV + n) * 2 + dd];
        out[(((t - 1) * NB + b) * NV + n) * 6 + c * 2 + dd] = acc;
    }
    __syncthreads();
    if (tid < 2) pcur[(b * NV + n) * 2 + tid] = s_psrc[n * 2 + tid];

    float pdx = s_psrc[n * 2 + 0], pdy = s_psrc[n * 2 + 1];

    // ---- vehicle pair weights (wave 0)
    if (tid < NV) {
        int s = tid;
        float relx = s_psrc[s * 2 + 0] - pdx, rely = s_psrc[s * 2 + 1] - pdy;
        float valid, win; int bin[4]; float cw[4];
        pair_geom(relx, rely, car_mask[b * NV + s], valid, win, bin, cw);
        float c = valid;
#pragma unroll
        for (int off = 32; off > 0; off >>= 1) c += __shfl_xor(c, off);
        float bw = valid * win / fmaxf(c, 1.0f);
        int base = (bn * NV + s) * 4;
#pragma unroll
        for (int q = 0; q < 4; ++q) { w4[base + q] = bw * cw[q]; bin4[base + q] = bin[q]; }
    }

    // ---- map: single pass (unnormalized accumulate + count)
    float lc = 0.0f;
    float* myG = &s_G4[(tid >> 6) * 96];
#pragma unroll
    for (int j = 0; j < NM / 256; ++j) {
        int s = tid + j * 256;
        float2 mp = *(const float2*)&map_p[(b * NM + s) * 2];
        float relx = mp.x - pdx, rely = mp.y - pdy;
        float valid, win; int bin[4]; float cw[4];
        pair_geom(relx, rely, map_mask[b * NM + s], valid, win, bin, cw);
        lc += valid;
        float ww = valid * win;
        if (ww > 0.0f) {
            float2 f2 = *(const float2*)&map_feat[(b * NM + s) * 2];
#pragma unroll
            for (int q = 0; q < 4; ++q) {
                float w = ww * cw[q];
                atomicAdd(&myG[bin[q] * 2 + 0], w * f2.x);
                atomicAdd(&myG[bin[q] * 2 + 1], w * f2.y);
            }
        }
    }
#pragma unroll
    for (int off = 32; off > 0; off >>= 1) lc += __shfl_xor(lc, off);
    if ((tid & 63) == 0) s_wred[tid >> 6] = lc;
    __syncthreads();
    if (tid < 96) s_G[tid] = s_G4[tid] + s_G4[96 + tid] + s_G4[192 + tid] + s_G4[288 + tid];
    __syncthreads();
    float invc = 1.0f / fmaxf(s_wred[0] + s_wred[1] + s_wred[2] + s_wred[3], 1.0f);

    // ---- map encoder contraction (Kmap direct from L2, coalesced float2)
    if (tid < 64) {
        float acc = 0.0f;
#pragma unroll 4
        for (int rt = 0; rt < RTOT; ++rt) {
            float2 k2 = *(const float2*)&Kmap[(rt * 64 + tid) * 2];
            acc = fmaf(k2.x, s_G[rt * 2 + 0], acc);
            acc = fmaf(k2.y, s_G[rt * 2 + 1], acc);
        }
        s_f2[128 + tid] = fmaxf(acc * invc, 0.0f);
    }
    // ---- back gate -> s_f2[0..127]
    if (tid >= 128) {
        int r = tid - 128, i = r >> 3, m = r & 7;
        float acc = 0.0f;
#pragma unroll
        for (int c = 0; c < 3; ++c)
#pragma unroll
            for (int l = 0; l < KR; ++l)
                acc = fmaf(WdBack[(i * 3 + c) * 8 + l], s_own[c * 8 + ((m - l) & 7)], acc);
        s_f2[r] = feat[(b * NV + n) * 192 + r] * tanhf(acc);
    }
    __syncthreads();
    if (tid < 192) feat[bn * 192 + tid] = s_f2[tid];

    // ---- fused vehicle-layer H for own source row
    if (doHv) {
        for (int p = tid; p < 384; p += 256) {
            float acc[KR];
#pragma unroll
            for (int m = 0; m < KR; ++m) acc[m] = 0.f;
#pragma unroll 4
            for (int i = 0; i < 24; ++i) {
                float4 k0 = KTv[(2 * i) * 384 + p];
                float4 k1 = KTv[(2 * i + 1) * 384 + p];
                float kk[8] = {k0.x, k0.y, k0.z, k0.w, k1.x, k1.y, k1.z, k1.w};
                float ff[8];
                *(float4*)&ff[0] = *(const float4*)&s_f2[i * 8];
                *(float4*)&ff[4] = *(const float4*)&s_f2[i * 8 + 4];
#pragma unroll
                for (int l = 0; l < KR; ++l) {
                    float kl = kk[l];
#pragma unroll
                    for (int m = 0; m < KR; ++m)
                        acc[m] = fmaf(kl, ff[(m - l) & 7], acc[m]);
                }
            }
            int rt = p >> 3, o = p & 7;
            float* hr = Hv + (size_t)(bn * RTOT + rt) * 64 + o * KR;
#pragma unroll
            for (int m = 0; m < KR; ++m) hr[m] = acc[m];
        }
    }
}

// ---------------------------------------------------------------------------
// One-time K transpose: KT[chunk j][pair p].  [R6 verbatim]
// ---------------------------------------------------------------------------
__global__ __launch_bounds__(256) void k_trans(
        const float* __restrict__ Kv, const float* __restrict__ K1g,
        const float* __restrict__ K2g, float4* __restrict__ KTv,
        float4* __restrict__ KT1, float4* __restrict__ KT2) {
    int idx = blockIdx.x * 256 + threadIdx.x;
    if (idx < 48 * 384) {
        int j = idx / 384, p = idx % 384;
        KTv[idx] = *(const float4*)(Kv + p * 192 + j * 4);
    } else if (idx < 48 * 384 + 16 * 384) {
        int r = idx - 48 * 384;
        int j = r / 384, p = r % 384;
        KT1[r] = *(const float4*)(K1g + p * 64 + j * 4);
    } else if (idx < 48 * 384 + 16 * 384 + 16 * 144) {
        int r = idx - (48 * 384 + 16 * 384);
        int j = r / 144, p = r % 144;
        KT2[r] = *(const float4*)(K2g + p * 64 + j * 4);
    }
}

// ---------------------------------------------------------------------------
// k_H: per-source vehicle-layer H (used at t=0 only).  [R6 proven]
// ---------------------------------------------------------------------------
__global__ __launch_bounds__(256) void k_H0(const float* __restrict__ inb,
        const float4* __restrict__ KT, float* __restrict__ H) {
    __shared__ __align__(16) float s_f[192];
    int bs = blockIdx.x, tid = threadIdx.x;
    if (tid < 192) s_f[tid] = inb[bs * 192 + tid];
    __syncthreads();
    for (int p = tid; p < 384; p += 256) {
        float acc[KR];
#pragma unroll
        for (int m = 0; m < KR; ++m) acc[m] = 0.f;
#pragma unroll 4
        for (int i = 0; i < 24; ++i) {
            float4 k0 = KT[(2 * i) * 384 + p];
            float4 k1 = KT[(2 * i + 1) * 384 + p];
            float kk[8] = {k0.x, k0.y, k0.z, k0.w, k1.x, k1.y, k1.z, k1.w};
            float ff[8];
            *(float4*)&ff[0] = *(const float4*)&s_f[i * 8];
            *(float4*)&ff[4] = *(const float4*)&s_f[i * 8 + 4];
#pragma unroll
            for (int l = 0; l < KR; ++l) {
                float kl = kk[l];
#pragma unroll
                for (int m = 0; m < KR; ++m)
                    acc[m] = fmaf(kl, ff[(m - l) & 7], acc[m]);
            }
        }
        int rt = p >> 3, o = p & 7;
        float* hr = H + (size_t)(bs * RTOT + rt) * 64 + o * KR;
#pragma unroll
        for (int m = 0; m < KR; ++m) hr[m] = acc[m];
    }
}

// ---------------------------------------------------------------------------
// k_aggH: fused [aggregate layer L -> out] + [H for layer L+1 from relu(out)].
// Phase 1: UNCONDITIONAL unrolled weighted sum (w==0 rows add exact 0.0;
// every H row is written each step before this kernel reads it).
// ---------------------------------------------------------------------------
template<int ICH, bool RELU_IN, bool RESID, int OCH2>
__global__ __launch_bounds__(256) void k_aggH(const float* __restrict__ inb,
        const float* __restrict__ H, const float* __restrict__ Wd,
        const float* __restrict__ w4, const int* __restrict__ bin4,
        const float4* __restrict__ KT2, float* __restrict__ outb,
        float* __restrict__ Hout) {
    constexpr int NC = ICH * KR;
    constexpr int HS = 64;                 // OCH = 8
    constexpr int NPAIR2 = RTOT * OCH2;    // 384 or 144
    constexpr int HS2 = OCH2 * KR;
    __shared__ float s_w[256];
    __shared__ int   s_row[256];           // precomputed H row index
    __shared__ float s_in[NC];
    __shared__ float s_part[4 * HS];
    __shared__ __align__(16) float s_f2[HS];
    int tid = threadIdx.x, bn = blockIdx.x, b = bn >> 6;
    s_w[tid] = w4[bn * 256 + tid];
    s_row[tid] = (b * NV + (tid >> 2)) * RTOT + bin4[bn * 256 + tid];
    if (tid < NC) s_in[tid] = inb[bn * NC + tid];
    __syncthreads();
    // ---- phase 1: aggregation (unconditional, pipelined loads)
    {
        int w = tid >> 6, c = tid & 63;
        float acc = 0.f;
#pragma unroll 8
        for (int j = 0; j < 64; ++j) {
            int idx = w * 64 + j;
            acc = fmaf(s_w[idx], H[(size_t)s_row[idx] * HS + c], acc);
        }
        s_part[w * HS + c] = acc;
    }
    __syncthreads();
    if (tid < HS) {
        float tot = s_part[tid] + s_part[HS + tid] + s_part[2 * HS + tid] + s_part[3 * HS + tid];
        int o = tid / KR, m = tid & 7;
#pragma unroll
        for (int i = 0; i < ICH; ++i) {
            const float* Wr = Wd + (o * ICH + i) * KR;
#pragma unroll
            for (int l = 0; l < KR; ++l) {
                float v = s_in[i * KR + ((m - l) & 7)];
                if (RELU_IN) v = fmaxf(v, 0.f);
                tot = fmaf(Wr[l], v, tot);
            }
        }
        if (RESID) tot += s_in[tid];
        outb[bn * HS + tid] = tot;
        s_f2[tid] = fmaxf(tot, 0.f);       // next layer consumes relu(out)
    }
    __syncthreads();
    // ---- phase 2: H for next layer (ICH2 = 8)
    for (int p = tid; p < NPAIR2; p += 256) {
        float acc2[KR];
#pragma unroll
        for (int m = 0; m < KR; ++m) acc2[m] = 0.f;
#pragma unroll 2
        for (int i = 0; i < 8; ++i) {
            float4 k0 = KT2[(2 * i) * NPAIR2 + p];
            float4 k1 = KT2[(2 * i + 1) * NPAIR2 + p];
            float kk[8] = {k0.x, k0.y, k0.z, k0.w, k1.x, k1.y, k1.z, k1.w};
            float ff[8];
            *(float4*)&ff[0] = *(const float4*)&s_f2[i * 8];
            *(float4*)&ff[4] = *(const float4*)&s_f2[i * 8 + 4];
#pragma unroll
            for (int l = 0; l < KR; ++l) {
                float kl = kk[l];
#pragma unroll
                for (int m = 0; m < KR; ++m)
                    acc2[m] = fmaf(kl, ff[(m - l) & 7], acc2[m]);
            }
        }
        int rt = p / OCH2, o = p - rt * OCH2;
        float* hr = Hout + (size_t)(bn * RTOT + rt) * HS2 + o * KR;
#pragma unroll
        for (int m = 0; m < KR; ++m) hr[m] = acc2[m];
    }
}

// ---------------------------------------------------------------------------
// k_agg: standalone aggregation (last layer, OCH=3), unconditional loads.
// ---------------------------------------------------------------------------
template<int ICH, int OCH, bool RELU_IN, bool RESID, bool RELU_OUT>
__global__ __launch_bounds__(256) void k_agg(const float* __restrict__ inb,
        const float* __restrict__ H, const float* __restrict__ Wd,
        const float* __restrict__ w4, const int* __restrict__ bin4,
        float* __restrict__ outb) {
    constexpr int NC = ICH * KR;
    constexpr int HS = OCH * KR;
    __shared__ float s_w[256];
    __shared__ int   s_row[256];
    __shared__ float s_in[NC];
    __shared__ float s_part[4 * HS];
    int tid = threadIdx.x, bn = blockIdx.x, b = bn >> 6;
    s_w[tid] = w4[bn * 256 + tid];
    s_row[tid] = (b * NV + (tid >> 2)) * RTOT + bin4[bn * 256 + tid];
    if (tid < NC) s_in[tid] = inb[bn * NC + tid];
    __syncthreads();
    int w = tid >> 6, c = tid & 63;
    if (c < HS) {
        float acc = 0.f;
#pragma unroll 8
        for (int j = 0; j < 64; ++j) {
            int idx = w * 64 + j;
            acc = fmaf(s_w[idx], H[(size_t)s_row[idx] * HS + c], acc);
        }
        s_part[w * HS + c] = acc;
    }
    __syncthreads();
    if (tid < HS) {
        float tot = s_part[tid] + s_part[HS + tid] + s_part[2 * HS + tid] + s_part[3 * HS + tid];
        int o = tid / KR, m = tid & 7;
#pragma unroll
        for (int i = 0; i < ICH; ++i) {
            const float* Wr = Wd + (o * ICH + i) * KR;
#pragma unroll
            for (int l = 0; l < KR; ++l) {
                float v = s_in[i * KR + ((m - l) & 7)];
                if (RELU_IN) v = fmaxf(v, 0.f);
                tot = fmaf(Wr[l], v, tot);
            }
        }
        if (RESID) tot += s_in[tid];
        if (RELU_OUT) tot = fmaxf(tot, 0.f);
        outb[bn * HS + tid] = tot;
    }
}

// ---------------------------------------------------------------------------
// FALLBACK PATH: fused conv (gather-then-contract).  [R3 verbatim]
// ---------------------------------------------------------------------------
template<int ICH, int OCH, bool RELU_IN, bool RESID, bool RELU_OUT>
__global__ __launch_bounds__(256) void k_conv(
        const float* __restrict__ inb, const float* __restrict__ Kg,
        const float* __restrict__ Wd, const float* __restrict__ w4,
        const int* __restrict__ bin4, float* __restrict__ outb) {
    constexpr int NC = ICH * KR;
    constexpr int NOUT = OCH * KR;
    constexpr int NQ = (OCH == 8) ? 32 : 64;
    constexpr int NG = 256 / NC;
    constexpr int GP = 12;

    __shared__ __align__(16) float G[RTOT * ICH * GP];
    __shared__ float s_w4[NV * 4];
    __shared__ int   s_b4[NV * 4];
    __shared__ __align__(16) float s_in[NC];

    int tid = threadIdx.x;
    int bn = blockIdx.x;
    int b = bn >> 6;

    for (int i = tid; i < RTOT * ICH * GP; i += 256) G[i] = 0.0f;
    s_w4[tid] = w4[bn * 256 + tid];
    s_b4[tid] = bin4[bn * 256 + tid];
    if (tid < NC) s_in[tid] = inb[bn * NC + tid];
    __syncthreads();

    if (tid < NC * NG) {
        int col = tid % NC, grp = tid / NC;
        int ci = col >> 3, cm = col & 7;
        for (int s = grp; s < NV; s += NG) {
            float v = inb[(b * NV + s) * NC + col];
            if (RELU_IN) v = fmaxf(v, 0.0f);
#pragma unroll
            for (int q = 0; q < 4; ++q) {
                float w = s_w4[s * 4 + q];
                if (w != 0.0f)
                    atomicAdd(&G[(s_b4[s * 4 + q] * ICH + ci) * GP + cm], w * v);
            }
        }
    }
    __syncthreads();

    const int q = tid & (NQ - 1);
    const int o = tid / NQ;
    if (o < OCH) {
        constexpr int ITERS = (RTOT * ICH) / NQ;
        float acc[KR];
#pragma unroll
        for (int m = 0; m < KR; ++m) acc[m] = 0.f;
#pragma unroll 2
        for (int j = 0; j < ITERS; ++j) {
            int f = j * NQ + q;
            int rt = f / ICH, i = f - rt * ICH;
            const float* Kr = Kg + ((rt * OCH + o) * ICH + i) * KR;
            const float* gr = &G[f * GP];
            float kk[8], gg[8];
            *(float4*)&kk[0] = *(const float4*)(Kr);
            *(float4*)&kk[4] = *(const float4*)(Kr + 4);
            *(float4*)&gg[0] = *(const float4*)(gr);
            *(float4*)&gg[4] = *(const float4*)(gr + 4);
#pragma unroll
            for (int l = 0; l < KR; ++l) {
                float kl = kk[l];
#pragma unroll
                for (int m = 0; m < KR; ++m)
                    acc[m] = fmaf(kl, gg[(m - l) & 7], acc[m]);
            }
        }
#pragma unroll
        for (int m = 0; m < KR; ++m) {
            acc[m] += __shfl_xor(acc[m], 1);
            acc[m] += __shfl_xor(acc[m], 2);
            acc[m] += __shfl_xor(acc[m], 4);
            acc[m] += __shfl_xor(acc[m], 8);
            acc[m] += __shfl_xor(acc[m], 16);
            if (NQ == 64) acc[m] += __shfl_xor(acc[m], 32);
        }
        if (q < KR) {
            float tot = acc[0];
#pragma unroll
            for (int m = 1; m < KR; ++m) if (q == m) tot = acc[m];
#pragma unroll
            for (int i = 0; i < ICH; ++i) {
                const float* Wr = Wd + (o * ICH + i) * KR;
#pragma unroll
                for (int l = 0; l < KR; ++l) {
                    float v = s_in[i * KR + ((q - l) & 7)];
                    if (RELU_IN) v = fmaxf(v, 0.0f);
                    tot = fmaf(Wr[l], v, tot);
                }
            }
            if (RESID) tot += s_in[o * KR + q];
            if (RELU_OUT) tot = fmaxf(tot, 0.f);
            outb[bn * NOUT + o * KR + q] = tot;
        }
    }
}

// ---------------------------------------------------------------------------
// FALLBACK advance (non-fused).  [R7 verbatim behavior via k_advHv doHv=0]
// ---------------------------------------------------------------------------

// ---------------------------------------------------------------------------
// Final write: outputs[29]
// ---------------------------------------------------------------------------
__global__ void k_final(const float* __restrict__ outD, const float* __restrict__ pcur,
                        const float* __restrict__ w_rho1, float* __restrict__ out) {
    int idx = blockIdx.x * blockDim.x + threadIdx.x;
    if (idx >= NB * NV * 6) return;
    int bn = idx / 6, r = idx % 6, c = r >> 1, dd = r & 1;
    float w0 = w_rho1[0], wq = w_rho1[1];
    float acc = 0.0f;
#pragma unroll
    for (int m = 0; m < KR; ++m) {
        float ang = TWO_PIF * (float)m / (float)KR;
        float sn, cs;
        sincosf(ang, &sn, &cs);
        float w2 = (dd == 0) ? (w0 * cs - wq * sn) : (w0 * sn + wq * cs);
        acc = fmaf(outD[bn * 24 + c * 8 + m], w2, acc);
    }
    if (c == 0) acc += pcur[bn * 2 + dd];
    out[(29 * NB * NV + bn) * 6 + r] = acc;
}

// ---------------------------------------------------------------------------
extern "C" void kernel_launch(void* const* d_in, const int* in_sizes, int n_in,
                              void* d_out, int out_size, void* d_ws, size_t ws_size,
                              hipStream_t stream) {
    const float* in_p     = (const float*)d_in[0];
    const float* in_feat  = (const float*)d_in[1];
    const float* map_p    = (const float*)d_in[2];
    const float* map_feat = (const float*)d_in[3];
    const float* car_mask = (const float*)d_in[4];
    const float* map_mask = (const float*)d_in[5];
    const float* Kv       = (const float*)d_in[6];
    const float* WdV      = (const float*)d_in[7];
    const float* K1       = (const float*)d_in[8];
    const float* Wd1      = (const float*)d_in[9];
    const float* K2       = (const float*)d_in[10];
    const float* Wd2      = (const float*)d_in[11];
    const float* WdBack   = (const float*)d_in[12];
    const float* w_rho1   = (const float*)d_in[13];
    const float* Kmap     = (const float*)d_in[14];

    float* ws   = (float*)d_ws;
    float* pbuf0 = ws;                       // 1024
    float* pbuf1 = ws + 1024;                // 1024
    float* feat  = ws + 2048;                // 98304  [512][192]
    float* out1  = ws + 100352;              // 32768  [512][64]
    float* out2  = ws + 133120;              // 32768  [512][64]
    float* outD  = ws + 165888;              // 12288  [512][24]
    float* w4    = ws + 178176;              // 131072 [512][256]
    int*   bin4  = (int*)(ws + 309248);      // 131072 ints -> ends 440320 fl
    float4* KTv  = (float4*)(ws + 440320);   // 73728 floats  [48][384] f4
    float4* KT1  = (float4*)(ws + 514048);   // 24576 floats  [16][384] f4
    float4* KT2  = (float4*)(ws + 538624);   // 9216 floats   [16][144] f4
    float* Hv    = ws + 547840;              // 1572864 [512][48][64]
    float* H1    = ws + 2120704;             // 1572864 [512][48][64]
    float* H2    = ws + 3693568;             // 589824  [512][48][24]
    float* out   = (float*)d_out;

    const size_t need_fast = (size_t)(3693568 + 589824) * sizeof(float); // 17.1 MB
    const bool fast = ws_size >= need_fast;

    hipMemcpyAsync(pbuf0, in_p, NB * NV * 2 * sizeof(float),
                   hipMemcpyDeviceToDevice, stream);
    hipMemcpyAsync(feat, in_feat, NB * NV * 24 * KR * sizeof(float),
                   hipMemcpyDeviceToDevice, stream);

    if (fast)
        k_trans<<<105, 256, 0, stream>>>(Kv, K1, K2, KTv, KT1, KT2);
    k_pairs0<<<NB * NV, 64, 0, stream>>>(pbuf0, car_mask, w4, bin4);

    auto decode_fast = [&]() {
        k_aggH<24, false, false, 8><<<NB * NV, 256, 0, stream>>>(feat, Hv, WdV, w4, bin4, KT1, out1, H1);
        k_aggH<8, true, true, 3><<<NB * NV, 256, 0, stream>>>(out1, H1, Wd1, w4, bin4, KT2, out2, H2);
        k_agg<8, 3, true, false, true><<<NB * NV, 256, 0, stream>>>(out2, H2, Wd2, w4, bin4, outD);
    };
    auto decode_safe = [&]() {
        k_conv<24, 8, false, false, false><<<NB * NV, 256, 0, stream>>>(feat, Kv, WdV, w4, bin4, out1);
        k_conv<8, 8, true, true, false><<<NB * NV, 256, 0, stream>>>(out1, K1, Wd1, w4, bin4, out2);
        k_conv<8, 3, true, false, true><<<NB * NV, 256, 0, stream>>>(out2, K2, Wd2, w4, bin4, outD);
    };

    if (fast) {
        k_H0<<<NB * NV, 256, 0, stream>>>(feat, KTv, Hv);
        decode_fast();
    } else {
        decode_safe();
    }

    for (int t = 1; t < 30; ++t) {
        float* pprev = (t & 1) ? pbuf0 : pbuf1;
        float* pcur  = (t & 1) ? pbuf1 : pbuf0;
        k_advHv<<<NB * NV, 256, 0, stream>>>(t, pprev, pcur, outD, feat,
                                             w_rho1, WdBack, Kmap, map_p, map_feat,
                                             map_mask, car_mask, w4, bin4, out,
                                             KTv, Hv, fast ? 1 : 0);
        if (fast) decode_fast(); else decode_safe();
    }
    k_final<<<12, 256, 0, stream>>>(outD, pbuf1, w_rho1, out);
}